// Round 2
// 255.083 us; speedup vs baseline: 1.0430x; 1.0430x over previous
//
#include <hip/hip_runtime.h>
#include <stdint.h>

// MultiHeadAttention: B=4, T=2048, C=1024, H=16, D=64, causal, scale=1/8.
// R10: flash -> in-register P with ZERO cross-lane ops: swapped QK^T
// (mfma(K,Q)) + permuted K-tile row order rho(p) in LDS so the in-lane
// pack of exp2(sc) is ALREADY the PV A-fragment (key relabeling trick).
// 2 q-tiles/block {bx,31-bx}, grid (64,16) -> 4 blocks/CU (LDS 32KB),
// K/V fragments shared across both q-tiles, s_setprio around MFMA.
//
// MFMA 16x16x32 bf16 layouts:
//   A frag: m = lane&15, k = (lane>>4)*8 + j
//   B frag: n = lane&15, k = (lane>>4)*8 + j
//   C/D:    col = lane&15, row = (lane>>4)*4 + reg
//
// rho: LDS K row p (bits b5..b0) holds key with bits b5,b3,b2,b4,b1,b0,
// i.e. pos (j,kq,lo) -> key 32*(j>>1) + 8*kq + 4*(j&1) + lo. Then lane
// (kq,mrow)'s sc[j][r] = S[key 32*(j>>1)+8kq+4*(j&1)+r][q=mrow], so
// pa0 = pack(sc[0],sc[1]) has element j' = key 8kq+j' and
// pa1 = pack(sc[2],sc[3]) has element j' = key 32+8kq+j' -- exactly the
// A-fragment for PV against natural-order V. No permlane/bpermute needed.

typedef __attribute__((ext_vector_type(8))) short bf16x8;
typedef __attribute__((ext_vector_type(4))) float f32x4;

#define EXP2F(x) __builtin_amdgcn_exp2f(x)
#define SL2E 0.18033688011112042f  /* 0.125 * log2(e) */
#define FIXED_M 15.0f

template <bool B> struct BoolC { static constexpr bool value = B; };

__device__ __forceinline__ short f2bf(float f) {
  union { float f; unsigned u; } c; c.f = f;
  unsigned u = c.u;
  unsigned r = (u + 0x7fffu + ((u >> 16) & 1u)) >> 16;
  return (short)(unsigned short)r;
}

// sc[j][r] = S at LDS K position 16j + 4kq + r, q = mrow (log2 units).
// Direct in-lane pack -> PV A-fragments (see rho comment above).
__device__ __forceinline__ void softmax_pack(const f32x4* sc, bf16x8& pa0, bf16x8& pa1) {
  union U { int i[4]; bf16x8 v; };
  U u0, u1;
#pragma unroll
  for (int j = 0; j < 4; ++j) {
    float p0 = EXP2F(sc[j][0]);
    float p1 = EXP2F(sc[j][1]);
    float p2 = EXP2F(sc[j][2]);
    float p3 = EXP2F(sc[j][3]);
    int w0, w1;
    asm("v_cvt_pk_bf16_f32 %0, %1, %2" : "=v"(w0) : "v"(p0), "v"(p1));
    asm("v_cvt_pk_bf16_f32 %0, %1, %2" : "=v"(w1) : "v"(p2), "v"(p3));
    if (j < 2) { u0.i[j * 2] = w0; u0.i[j * 2 + 1] = w1; }
    else       { u1.i[(j - 2) * 2] = w0; u1.i[(j - 2) * 2 + 1] = w1; }
  }
  pa0 = u0.v;
  pa1 = u1.v;
}

// async 16B global -> LDS (dest = wave-uniform base + lane*16)
__device__ __forceinline__ void llds16(const short* g, short* l) {
  __builtin_amdgcn_global_load_lds(
      (const __attribute__((address_space(1))) unsigned int*)g,
      (__attribute__((address_space(3))) unsigned int*)l, 16, 0, 0);
}

__global__ __launch_bounds__(256) void cast_f32_to_bf16(
    const float* __restrict__ src, short* __restrict__ dst, int n4) {
  int i = blockIdx.x * 256 + threadIdx.x;
  if (i >= n4) return;
  float4 f = ((const float4*)src)[i];
  short4 o;
  o.x = f2bf(f.x); o.y = f2bf(f.y); o.z = f2bf(f.z); o.w = f2bf(f.w);
  ((short4*)dst)[i] = o;
}

// ---------------------------------------------------------------------------
// QKV GEMM (B^T): C[m,n] = sum_k A[m,k]*Bw[n,k]. 128x128 tile, BK=32,
// DOUBLE-BUFFERED staging (1 barrier/iter), XOR-swizzled, LDS union with
// corner-turn epilogue (34 KB total -> 4 blocks/CU). Q/K: row-major lC ->
// [B,H,T,D] (K pre-scaled by SL2E). V (n0>=2048): transposed lCt -> Vt.
// ---------------------------------------------------------------------------
__global__ __launch_bounds__(256) void gemm_qkv(
    const short* __restrict__ A, const short* __restrict__ Bw,
    short* __restrict__ Qo, short* __restrict__ Ko, short* __restrict__ Vt) {
  const int K = 1024;
  __shared__ short smem[17408];  // [buf0: A 4096|B 4096][buf1: A 4096|B 4096] | lC/lCt
  const int tid = threadIdx.x;
  const int lane = tid & 63;
  const int wave = tid >> 6;
  const int m0 = blockIdx.y * 128;
  const int n0 = blockIdx.x * 128;
  const int wm = (wave >> 1) * 64;
  const int wn = (wave & 1) * 64;
  const int mrow = lane & 15;
  const int kq = lane >> 4;

  f32x4 acc[4][4];
#pragma unroll
  for (int i = 0; i < 4; ++i)
#pragma unroll
    for (int j = 0; j < 4; ++j) acc[i][j] = (f32x4){0.f, 0.f, 0.f, 0.f};

  // stage tile it (k0 = it*32) into buffer buf: 512 chunks of 8 shorts each
  auto stage = [&](int it, int buf) {
#pragma unroll
    for (int call = 0; call < 2; ++call) {
      const int cb = call * 256 + wave * 64;
      const int c = cb + lane;
      const int row = c >> 2;
      const int scol = (c & 3) ^ (row & 3);
      llds16(A + (size_t)(m0 + row) * K + it * 32 + scol * 8,
             &smem[buf * 8192 + cb * 8]);
      llds16(Bw + (size_t)(n0 + row) * K + it * 32 + scol * 8,
             &smem[buf * 8192 + 4096 + cb * 8]);
    }
  };

  stage(0, 0);
  __syncthreads();

  for (int it = 0; it < 32; ++it) {
    const int buf = it & 1;
    if (it < 31) stage(it + 1, buf ^ 1);
    const short* lA = &smem[buf * 8192];
    const short* lB = &smem[buf * 8192 + 4096];
    bf16x8 af[4], bfr[4];
#pragma unroll
    for (int i = 0; i < 4; ++i) {
      const int row = wm + i * 16 + mrow;
      af[i] = *(const bf16x8*)&lA[row * 32 + ((kq ^ (row & 3)) * 8)];
    }
#pragma unroll
    for (int j = 0; j < 4; ++j) {
      const int row = wn + j * 16 + mrow;
      bfr[j] = *(const bf16x8*)&lB[row * 32 + ((kq ^ (row & 3)) * 8)];
    }
#pragma unroll
    for (int i = 0; i < 4; ++i)
#pragma unroll
      for (int j = 0; j < 4; ++j)
        acc[i][j] = __builtin_amdgcn_mfma_f32_16x16x32_bf16(af[i], bfr[j], acc[i][j], 0, 0, 0);
    __syncthreads();
  }

  const int b = m0 >> 11;            // whole tile lies in one batch
  if (n0 < 2048) {
    // Q/K block: row-major corner-turn (stride 132), coalesced 16B stores
    short* lC = smem;
#pragma unroll
    for (int i = 0; i < 4; ++i) {
      const int row = wm + i * 16 + kq * 4;
#pragma unroll
      for (int j = 0; j < 4; ++j) {
        const int col = wn + j * 16 + mrow;
        const float sc_ = (((n0 + col) >> 10) == 1) ? SL2E : 1.0f;
#pragma unroll
        for (int r = 0; r < 4; ++r)
          lC[(row + r) * 132 + col] = f2bf(acc[i][j][r] * sc_);
      }
    }
    __syncthreads();
#pragma unroll
    for (int call = 0; call < 8; ++call) {
      const int cc = call * 256 + tid;
      const int row = cc >> 4;
      const int t = (m0 + row) & 2047;
      const int o = n0 + (cc & 15) * 8;
      const int c = o & 1023;
      const int h = c >> 6;
      const int d = c & 63;
      short* dst = (o >> 10) == 0 ? Qo : Ko;
      bf16x8 val = *(const bf16x8*)&lC[row * 132 + (cc & 15) * 8];
      *(bf16x8*)(dst + ((size_t)(b * 16 + h) * 2048 + t) * 64 + d) = val;
    }
  } else {
    // V block: transposed corner-turn (lCt[col][row], stride 136) -> Vt [bh][d][t]
    short* lCt = smem;
#pragma unroll
    for (int i = 0; i < 4; ++i) {
      const int row = wm + i * 16 + kq * 4;
#pragma unroll
      for (int j = 0; j < 4; ++j) {
        const int col = wn + j * 16 + mrow;
#pragma unroll
        for (int r = 0; r < 4; ++r)
          lCt[col * 136 + row + r] = f2bf(acc[i][j][r]);
      }
    }
    __syncthreads();
#pragma unroll
    for (int call = 0; call < 8; ++call) {
      const int cc = call * 256 + tid;
      const int col = cc >> 4;
      const int tg = cc & 15;
      const int o = n0 + col;           // 2048..3071
      const int d = o & 63;
      const int h = (o >> 6) & 15;
      const int t = (m0 & 2047) + tg * 8;   // batch offset lives in bh, not t
      bf16x8 val = *(const bf16x8*)&lCt[col * 136 + tg * 8];
      *(bf16x8*)(Vt + ((size_t)(b * 16 + h) * 64 + d) * 2048 + t) = val;
    }
  }
}

// Out-proj GEMM: M=8192, N=1024, BK=32, double-buffered staging, + bias, fp32.
__global__ __launch_bounds__(256) void gemm_out(
    const short* __restrict__ A, const short* __restrict__ Bw,
    const float* __restrict__ bias, float* __restrict__ Out) {
  const int K = 1024;
  __shared__ short smem[16384];
  const int tid = threadIdx.x;
  const int lane = tid & 63;
  const int wave = tid >> 6;
  const int m0 = blockIdx.y * 128;
  const int n0 = blockIdx.x * 128;
  const int wm = (wave >> 1) * 64;
  const int wn = (wave & 1) * 64;
  const int mrow = lane & 15;
  const int kq = lane >> 4;

  f32x4 acc[4][4];
#pragma unroll
  for (int i = 0; i < 4; ++i)
#pragma unroll
    for (int j = 0; j < 4; ++j) acc[i][j] = (f32x4){0.f, 0.f, 0.f, 0.f};

  auto stage = [&](int it, int buf) {
#pragma unroll
    for (int call = 0; call < 2; ++call) {
      const int cb = call * 256 + wave * 64;
      const int c = cb + lane;
      const int row = c >> 2;
      const int scol = (c & 3) ^ (row & 3);
      llds16(A + (size_t)(m0 + row) * K + it * 32 + scol * 8,
             &smem[buf * 8192 + cb * 8]);
      llds16(Bw + (size_t)(n0 + row) * K + it * 32 + scol * 8,
             &smem[buf * 8192 + 4096 + cb * 8]);
    }
  };

  stage(0, 0);
  __syncthreads();

  for (int it = 0; it < 32; ++it) {
    const int buf = it & 1;
    if (it < 31) stage(it + 1, buf ^ 1);
    const short* lA = &smem[buf * 8192];
    const short* lB = &smem[buf * 8192 + 4096];
    bf16x8 af[4], bfr[4];
#pragma unroll
    for (int i = 0; i < 4; ++i) {
      const int row = wm + i * 16 + mrow;
      af[i] = *(const bf16x8*)&lA[row * 32 + ((kq ^ (row & 3)) * 8)];
    }
#pragma unroll
    for (int j = 0; j < 4; ++j) {
      const int row = wn + j * 16 + mrow;
      bfr[j] = *(const bf16x8*)&lB[row * 32 + ((kq ^ (row & 3)) * 8)];
    }
#pragma unroll
    for (int i = 0; i < 4; ++i)
#pragma unroll
      for (int j = 0; j < 4; ++j)
        acc[i][j] = __builtin_amdgcn_mfma_f32_16x16x32_bf16(af[i], bfr[j], acc[i][j], 0, 0, 0);
    __syncthreads();
  }

#pragma unroll
  for (int i = 0; i < 4; ++i) {
    const int m = m0 + wm + i * 16 + kq * 4;
#pragma unroll
    for (int j = 0; j < 4; ++j) {
      const int n = n0 + wn + j * 16 + mrow;
      const float bb = bias[n];
#pragma unroll
      for (int r = 0; r < 4; ++r)
        Out[(size_t)(m + r) * 1024 + n] = acc[i][j][r] + bb;
    }
  }
}

// ---------------------------------------------------------------------------
// Flash attention R10. Grid (64 bh, 16). Block handles TWO q-tiles
// {bx, 31-bx} (constant 33 seg-iterations), one K/Vt stream (kt = 0..31-bx).
// Swapped QK^T (mfma(K,Q)) with rho-permuted K rows: softmax fully
// in-register with NO cross-lane ops. K/V fragments loaded ONCE per kt,
// shared by both q-tiles. Fixed-max softmax (M=15 via MFMA C-init);
// l via ones-MFMA over packed P. Double-buffered staging, one barrier
// per kt. LDS = 32 KB -> 4 blocks/CU.
// ---------------------------------------------------------------------------
__global__ __launch_bounds__(256) void flash_attn(
    const short* __restrict__ Qg, const short* __restrict__ Kg,
    const short* __restrict__ Vtg, short* __restrict__ Og) {
  const int T = 2048;
  __shared__ short lK[2][64 * 64];
  __shared__ short lVt[2][64 * 64];
  const int tid = threadIdx.x;
  const int lane = tid & 63;
  const int wave = tid >> 6;
  const int bh = blockIdx.x;
  const int bx = blockIdx.y;         // 0..15
  const int mrow = lane & 15;
  const int kq = lane >> 4;
  const int swz = mrow & 7;
  const size_t base = (size_t)bh * T * 64;   // Q,K: [bh][t][d]
  const size_t vbase = (size_t)bh * 64 * T;  // Vt:  [bh][d][t]

  const int qt0 = bx;        // active for kt <= qt0
  const int qt1 = 31 - bx;   // active for all kt (ktmax = qt1)

  const bf16x8 ones = {0x3F80, 0x3F80, 0x3F80, 0x3F80, 0x3F80, 0x3F80, 0x3F80, 0x3F80};

  bf16x8 aq0_0, aq1_0, aq0_1, aq1_1;
  {
    const short* qp0 = Qg + base + (size_t)(qt0 * 64 + wave * 16 + mrow) * 64 + kq * 8;
    aq0_0 = *(const bf16x8*)qp0;
    aq1_0 = *(const bf16x8*)(qp0 + 32);
    const short* qp1 = Qg + base + (size_t)(qt1 * 64 + wave * 16 + mrow) * 64 + kq * 8;
    aq0_1 = *(const bf16x8*)qp1;
    aq1_1 = *(const bf16x8*)(qp1 + 32);
  }

  f32x4 acc0[4], acc1[4], lac0, lac1;
  lac0 = (f32x4){0.f, 0.f, 0.f, 0.f};
  lac1 = (f32x4){0.f, 0.f, 0.f, 0.f};
#pragma unroll
  for (int jd = 0; jd < 4; ++jd) {
    acc0[jd] = (f32x4){0.f, 0.f, 0.f, 0.f};
    acc1[jd] = (f32x4){0.f, 0.f, 0.f, 0.f};
  }

  auto stage = [&](int nt, int buf) {
#pragma unroll
    for (int call = 0; call < 2; ++call) {
      const int cb = call * 256 + wave * 64;
      const int c = cb + lane;
      const int row = c >> 3;
      const int scol = (c & 7) ^ (row & 7);
      // K row permutation rho: LDS row p holds key with bit-permuted index
      // (b5,b4,b3,b2 -> b5,b3,b2,b4) so the in-lane P pack IS the PV A-frag.
      const int grow = (row & 0x23) | ((row & 0x0C) << 1) | ((row & 0x10) >> 2);
      llds16(Kg + base + (size_t)(nt * 64 + grow) * 64 + scol * 8, &lK[buf][cb * 8]);
      llds16(Vtg + vbase + (size_t)row * T + nt * 64 + scol * 8, &lVt[buf][cb * 8]);
    }
  };

  stage(0, 0);
  __syncthreads();

  auto seg = [&](auto A, const short* K_, const short* Vt_, int kt) {
    constexpr bool ACT0 = decltype(A)::value;
    // ---- QK^T (swapped: A = K rows -> D row = K-LDS position, col = q) ----
    f32x4 sc0[4], sc1[4];
#pragma unroll
    for (int j = 0; j < 4; ++j) {
      const short* krow = &K_[(j * 16 + mrow) * 64];
      bf16x8 kb0 = *(const bf16x8*)&krow[(kq ^ swz) * 8];
      bf16x8 kb1 = *(const bf16x8*)&krow[((4 + kq) ^ swz) * 8];
      __builtin_amdgcn_s_setprio(1);
      f32x4 ss = (f32x4){-FIXED_M, -FIXED_M, -FIXED_M, -FIXED_M};
      ss = __builtin_amdgcn_mfma_f32_16x16x32_bf16(kb0, aq0_1, ss, 0, 0, 0);
      ss = __builtin_amdgcn_mfma_f32_16x16x32_bf16(kb1, aq1_1, ss, 0, 0, 0);
      sc1[j] = ss;
      if constexpr (ACT0) {
        f32x4 s2 = (f32x4){-FIXED_M, -FIXED_M, -FIXED_M, -FIXED_M};
        s2 = __builtin_amdgcn_mfma_f32_16x16x32_bf16(kb0, aq0_0, s2, 0, 0, 0);
        s2 = __builtin_amdgcn_mfma_f32_16x16x32_bf16(kb1, aq1_0, s2, 0, 0, 0);
        sc0[j] = s2;
      }
      __builtin_amdgcn_s_setprio(0);
    }

    // ---- causal masks (diagonal tiles). sc[j][r] is key
    // kt*64 + 32*(j>>1) + 8*kq + 4*(j&1) + r under rho. ----
    if (kt == qt1) {
      const int qcol = qt1 * 64 + wave * 16 + mrow;
#pragma unroll
      for (int j = 0; j < 4; ++j) {
        const int keyb = kt * 64 + ((j & 2) << 4) + (kq << 3) + ((j & 1) << 2);
#pragma unroll
        for (int r = 0; r < 4; ++r)
          if (keyb + r > qcol) sc1[j][r] = -1e30f;
      }
    }
    if constexpr (ACT0) {
      if (kt == qt0) {
        const int qcol = qt0 * 64 + wave * 16 + mrow;
#pragma unroll
        for (int j = 0; j < 4; ++j) {
          const int keyb = kt * 64 + ((j & 2) << 4) + (kq << 3) + ((j & 1) << 2);
#pragma unroll
          for (int r = 0; r < 4; ++r)
            if (keyb + r > qcol) sc0[j][r] = -1e30f;
        }
      }
    }

    // ---- softmax: exp2 + direct in-lane pack (no shuffles) ----
    bf16x8 pa0_1, pa1_1, pa0_0, pa1_0;
    softmax_pack(sc1, pa0_1, pa1_1);
    lac1 = __builtin_amdgcn_mfma_f32_16x16x32_bf16(pa0_1, ones, lac1, 0, 0, 0);
    lac1 = __builtin_amdgcn_mfma_f32_16x16x32_bf16(pa1_1, ones, lac1, 0, 0, 0);
    if constexpr (ACT0) {
      softmax_pack(sc0, pa0_0, pa1_0);
      lac0 = __builtin_amdgcn_mfma_f32_16x16x32_bf16(pa0_0, ones, lac0, 0, 0, 0);
      lac0 = __builtin_amdgcn_mfma_f32_16x16x32_bf16(pa1_0, ones, lac0, 0, 0, 0);
    }

    // ---- PV: V fragments loaded once, shared by both q-tiles ----
#pragma unroll
    for (int jd = 0; jd < 4; ++jd) {
      const short* vrow = &Vt_[(jd * 16 + mrow) * 64];
      bf16x8 vb0 = *(const bf16x8*)&vrow[(kq ^ swz) * 8];
      bf16x8 vb1 = *(const bf16x8*)&vrow[((4 + kq) ^ swz) * 8];
      __builtin_amdgcn_s_setprio(1);
      acc1[jd] = __builtin_amdgcn_mfma_f32_16x16x32_bf16(pa0_1, vb0, acc1[jd], 0, 0, 0);
      acc1[jd] = __builtin_amdgcn_mfma_f32_16x16x32_bf16(pa1_1, vb1, acc1[jd], 0, 0, 0);
      if constexpr (ACT0) {
        acc0[jd] = __builtin_amdgcn_mfma_f32_16x16x32_bf16(pa0_0, vb0, acc0[jd], 0, 0, 0);
        acc0[jd] = __builtin_amdgcn_mfma_f32_16x16x32_bf16(pa1_0, vb1, acc0[jd], 0, 0, 0);
      }
      __builtin_amdgcn_s_setprio(0);
    }
  };

  for (int kt = 0; kt <= qt1; ++kt) {
    const int bcur = kt & 1;
    if (kt < qt1) stage(kt + 1, bcur ^ 1);
    if (kt <= qt0) seg(BoolC<true>{}, lK[bcur], lVt[bcur], kt);
    else           seg(BoolC<false>{}, lK[bcur], lVt[bcur], kt);
    __syncthreads();
  }

  const int b = bh >> 4;
  const int h = bh & 15;
#pragma unroll
  for (int r = 0; r < 4; ++r) {
    const float inv0 = 1.0f / lac0[r];
    const int t0 = qt0 * 64 + wave * 16 + kq * 4 + r;
#pragma unroll
    for (int jd = 0; jd < 4; ++jd) {
      const int col = h * 64 + jd * 16 + mrow;
      Og[((size_t)b * 2048 + t0) * 1024 + col] = f2bf(acc0[jd][r] * inv0);
    }
    const float inv1 = 1.0f / lac1[r];
    const int t1 = qt1 * 64 + wave * 16 + kq * 4 + r;
#pragma unroll
    for (int jd = 0; jd < 4; ++jd) {
      const int col = h * 64 + jd * 16 + mrow;
      Og[((size_t)b * 2048 + t1) * 1024 + col] = f2bf(acc1[jd][r] * inv1);
    }
  }
}

extern "C" void kernel_launch(void* const* d_in, const int* in_sizes, int n_in,
                              void* d_out, int out_size, void* d_ws, size_t ws_size,
                              hipStream_t stream) {
  const float* x = (const float*)d_in[0];
  const float* w_qkv = (const float*)d_in[1];
  const float* w_out = (const float*)d_in[2];
  const float* b_out = (const float*)d_in[3];
  float* out = (float*)d_out;

  char* ws = (char*)d_ws;
  const size_t NX = 8192ull * 1024;
  const size_t NWQ = 3072ull * 1024;
  const size_t NWO = 1024ull * 1024;
  const size_t NQ = 64ull * 2048 * 64;
  size_t off = 0;
  short* xb    = (short*)(ws + off); off += NX * 2;
  short* wqkvb = (short*)(ws + off); off += NWQ * 2;
  short* woutb = (short*)(ws + off); off += NWO * 2;
  short* q     = (short*)(ws + off); off += NQ * 2;
  short* k     = (short*)(ws + off); off += NQ * 2;
  short* vt    = (short*)(ws + off); off += NQ * 2;  // V stored transposed [bh][d][t]
  short* attb  = (short*)(ws + off); off += NX * 2;
  if (off > ws_size) return;

  cast_f32_to_bf16<<<(int)(NX / 4 / 256), 256, 0, stream>>>(x, xb, (int)(NX / 4));
  cast_f32_to_bf16<<<(int)(NWQ / 4 / 256), 256, 0, stream>>>(w_qkv, wqkvb, (int)(NWQ / 4));
  cast_f32_to_bf16<<<(int)(NWO / 4 / 256), 256, 0, stream>>>(w_out, woutb, (int)(NWO / 4));
  gemm_qkv<<<dim3(24, 64), 256, 0, stream>>>(xb, wqkvb, q, k, vt);
  flash_attn<<<dim3(64, 16), 256, 0, stream>>>(q, k, vt, attb);
  gemm_out<<<dim3(8, 64), 256, 0, stream>>>(attb, woutb, b_out, out);
}